// Round 5
// baseline (447.562 us; speedup 1.0000x reference)
//
#include <hip/hip_runtime.h>
#include <hip/hip_bf16.h>
#include <cstdint>

#define N_ATOMS 100000
#define NFEAT   256
#define NMOL    1024
#define UNITS   3128    // 100096 / 32 rows per unit
#define NBLK    196     // ceil(3128 / 16 waves)

static constexpr float SCALE_C = 5.992277830325989f;
static constexpr float SHIFT_C = -406274.63784969115f;

typedef __attribute__((ext_vector_type(8))) short short8;    // bf16x8 MFMA operand
typedef __attribute__((ext_vector_type(4))) float float4_t;  // f32x4 accumulator

__device__ __forceinline__ unsigned short f2bf(float x) {
    union { float f; uint32_t u; } v; v.f = x;
    uint32_t r = (v.u + 0x7fffu + ((v.u >> 16) & 1u)) >> 16;
    return (unsigned short)r;
}

// pack two fp32 -> two bf16 (round-half-up) in one v_perm
__device__ __forceinline__ uint32_t pk(float lo, float hi) {
    union { float f; uint32_t u; } a, b; a.f = lo; b.f = hi;
    return __builtin_amdgcn_perm(b.u + 0x8000u, a.u + 0x8000u, 0x07060302u);
}

__device__ __forceinline__ float silu(float x) {
    return x / (1.0f + __expf(-x));
}

// async global->LDS, 16B/lane; LDS dest wave-uniform, lane i lands at +i*16B
__device__ __forceinline__ void async16(void* lds, const void* g) {
    __builtin_amdgcn_global_load_lds(
        (const __attribute__((address_space(1))) unsigned int*)(uintptr_t)g,
        (__attribute__((address_space(3))) unsigned int*)(uint32_t)(uintptr_t)lds,
        16, 0, 0);
}

// W image layout (prep output; shorts): plane(k>>7)*32768 + n*128 +
//   (((k>>3)&15 ^ (n&15))<<3) + (k&7).  Verified zero-conflict R2-R4.
__device__ __forceinline__ short8 wfrag(const unsigned short* Wlds, int n, int kc) {
    return *(const short8*)&Wlds[((kc >> 4) << 15) + n * 128 +
                                 ((((kc & 15) ^ (n & 15)) & 15) << 3)];
}

// ---------------------------------------------------------------------------
// Prep: W1,W2 fp32 [k][n] -> bf16 swizzled plane images; init out[] = SHIFT.
// ---------------------------------------------------------------------------
__global__ void prep(const float* __restrict__ W1, const float* __restrict__ W2,
                     unsigned short* __restrict__ W1i, unsigned short* __restrict__ W2i,
                     float* __restrict__ out) {
    int g = blockIdx.x * 256 + threadIdx.x;          // 0 .. 131071
    const float* W = (g < 65536) ? W1 : W2;
    unsigned short* Wi = (g < 65536) ? W1i : W2i;
    int idx = g & 65535;
    int k = idx >> 8, n = idx & 255;
    int kc = (k >> 3) & 15;
    int pos = ((k >> 7) << 15) + n * 128 + (((kc ^ (n & 15)) & 15) << 3) + (k & 7);
    Wi[pos] = f2bf(W[idx]);
    if (g < NMOL) out[g] = SHIFT_C;
}

// ---------------------------------------------------------------------------
// Layer 1: H1 = silu(A @ W1 + b1). 1024 thr = 16 waves, 1 block/CU,
// W1 (128 KB) in LDS staged once. Each wave: ONE static 32x256 unit,
// straight-line body, all 32 A-loads hoisted ahead of compute.
// Swapped MFMA operands so each lane's acc holds 4 consecutive H1 cols.
// ---------------------------------------------------------------------------
__global__ __launch_bounds__(1024, 1)
void mlp1(const float* __restrict__ A, const unsigned short* __restrict__ Wimg,
          const float* __restrict__ b1, unsigned short* __restrict__ H1) {
    __shared__ unsigned short Wlds[65536];   // 128 KB

    const int tid = threadIdx.x;
    const int w = tid >> 6, lane = tid & 63;
    const int fl = lane & 15, qd = lane >> 4;

#pragma unroll
    for (int i = 0; i < 8; ++i)
        async16(&Wlds[i * 8192 + w * 512], Wimg + i * 8192 + w * 512 + lane * 8);
    __syncthreads();

    const int u = blockIdx.x * 16 + w;
    if (u >= UNITS) return;
    const int rbase = u * 32;

    // ---- hoist ALL global A loads (32 x float4) ----
    float4 va[8][2][2];
#pragma unroll
    for (int s = 0; s < 8; ++s)
#pragma unroll
        for (int j = 0; j < 2; ++j) {
            int row = rbase + j * 16 + fl;
            const float* p = A + (size_t)row * 256 + s * 32 + qd * 8;
            if (row < N_ATOMS) {
                va[s][j][0] = *(const float4*)p;
                va[s][j][1] = *(const float4*)(p + 4);
            } else {
                va[s][j][0] = make_float4(0.f, 0.f, 0.f, 0.f);
                va[s][j][1] = make_float4(0.f, 0.f, 0.f, 0.f);
            }
        }

    float4_t acc[16][2] = {};   // [col-tile][row-tile]
#pragma unroll
    for (int s = 0; s < 8; ++s) {
        const int kc = s * 4 + qd;
        short8 af[2];
#pragma unroll
        for (int j = 0; j < 2; ++j) {
            union { uint32_t u4[4]; short8 s8; } cv;
            cv.u4[0] = pk(va[s][j][0].x, va[s][j][0].y);
            cv.u4[1] = pk(va[s][j][0].z, va[s][j][0].w);
            cv.u4[2] = pk(va[s][j][1].x, va[s][j][1].y);
            cv.u4[3] = pk(va[s][j][1].z, va[s][j][1].w);
            af[j] = cv.s8;
        }
#pragma unroll
        for (int i = 0; i < 16; ++i) {
            short8 wf = wfrag(Wlds, i * 16 + fl, kc);
            acc[i][0] = __builtin_amdgcn_mfma_f32_16x16x32_bf16(wf, af[0], acc[i][0], 0, 0, 0);
            acc[i][1] = __builtin_amdgcn_mfma_f32_16x16x32_bf16(wf, af[1], acc[i][1], 0, 0, 0);
        }
    }

    // acc[i][j]: atom = rbase + j*16 + fl, col = i*16 + qd*4 + r
#pragma unroll
    for (int i = 0; i < 16; ++i) {
        int nb = i * 16 + qd * 4;
        float4 b4 = *(const float4*)&b1[nb];
#pragma unroll
        for (int j = 0; j < 2; ++j) {
            int atom = rbase + j * 16 + fl;
            if (atom < N_ATOMS) {
                uint2 o;
                o.x = pk(silu(acc[i][j][0] + b4.x), silu(acc[i][j][1] + b4.y));
                o.y = pk(silu(acc[i][j][2] + b4.z), silu(acc[i][j][3] + b4.w));
                *(uint2*)&H1[(size_t)atom * 256 + nb] = o;
            }
        }
    }
}

// ---------------------------------------------------------------------------
// Layer 2+3+pool: out[mol] += SCALE*(silu(H1@W2+b2).W3 + b3). Same structure:
// one static unit per wave, 16 H1 loads hoisted; epilogue silu·W3,
// fl-butterfly reduce, one atomicAdd per atom.
// ---------------------------------------------------------------------------
__global__ __launch_bounds__(1024, 1)
void mlp2(const unsigned short* __restrict__ H1, const unsigned short* __restrict__ Wimg,
          const float* __restrict__ b2, const float* __restrict__ W3,
          const float* __restrict__ b3, const int* __restrict__ batch,
          float* __restrict__ out) {
    __shared__ unsigned short Wlds[65536];   // 128 KB

    const int tid = threadIdx.x;
    const int w = tid >> 6, lane = tid & 63;
    const int fl = lane & 15, qd = lane >> 4;

#pragma unroll
    for (int i = 0; i < 8; ++i)
        async16(&Wlds[i * 8192 + w * 512], Wimg + i * 8192 + w * 512 + lane * 8);
    __syncthreads();

    const int u = blockIdx.x * 16 + w;
    if (u >= UNITS) return;
    const int rbase = u * 32;

    // ---- hoist ALL global H1 loads (16 x short8) ----
    short8 hf[8][2];
#pragma unroll
    for (int s = 0; s < 8; ++s)
#pragma unroll
        for (int j = 0; j < 2; ++j) {
            int row = rbase + j * 16 + fl;
            if (row < N_ATOMS)
                hf[s][j] = *(const short8*)&H1[(size_t)row * 256 + s * 32 + qd * 8];
            else
                hf[s][j] = (short8){0, 0, 0, 0, 0, 0, 0, 0};
        }

    const float b3v = b3[0];
    float bbv[16], w3v[16];
#pragma unroll
    for (int i = 0; i < 16; ++i) {
        bbv[i] = b2[i * 16 + fl];
        w3v[i] = W3[i * 16 + fl];
    }

    float4_t acc[2][16] = {};   // [row-tile][col-tile]
#pragma unroll
    for (int s = 0; s < 8; ++s) {
        const int kc = s * 4 + qd;
#pragma unroll
        for (int i = 0; i < 16; ++i) {
            short8 wf = wfrag(Wlds, i * 16 + fl, kc);
            acc[0][i] = __builtin_amdgcn_mfma_f32_16x16x32_bf16(hf[s][0], wf, acc[0][i], 0, 0, 0);
            acc[1][i] = __builtin_amdgcn_mfma_f32_16x16x32_bf16(hf[s][1], wf, acc[1][i], 0, 0, 0);
        }
    }

    // acc[j][i]: atom = rbase + j*16 + qd*4 + r, col = i*16 + fl
    float rs[2][4] = {};
#pragma unroll
    for (int i = 0; i < 16; ++i)
#pragma unroll
        for (int j = 0; j < 2; ++j)
#pragma unroll
            for (int r = 0; r < 4; ++r)
                rs[j][r] += silu(acc[j][i][r] + bbv[i]) * w3v[i];

#pragma unroll
    for (int j = 0; j < 2; ++j)
#pragma unroll
        for (int r = 0; r < 4; ++r) {
            float v = rs[j][r];
            v += __shfl_xor(v, 1);
            v += __shfl_xor(v, 2);
            v += __shfl_xor(v, 4);
            v += __shfl_xor(v, 8);
            rs[j][r] = v;
        }
    // butterfly = allreduce over fl; lane fl == j*4+r posts that atom's add
#pragma unroll
    for (int j = 0; j < 2; ++j)
#pragma unroll
        for (int r = 0; r < 4; ++r)
            if (fl == j * 4 + r) {
                int atom = rbase + j * 16 + qd * 4 + r;
                if (atom < N_ATOMS)
                    atomicAdd(&out[batch[atom]], (rs[j][r] + b3v) * SCALE_C);
            }
}

// ---------------------------------------------------------------------------
extern "C" void kernel_launch(void* const* d_in, const int* in_sizes, int n_in,
                              void* d_out, int out_size, void* d_ws, size_t ws_size,
                              hipStream_t stream) {
    const float* A     = (const float*)d_in[0];
    const int*   batch = (const int*)d_in[1];
    const float* W1    = (const float*)d_in[2];
    const float* b1    = (const float*)d_in[3];
    const float* W2    = (const float*)d_in[4];
    const float* b2    = (const float*)d_in[5];
    const float* W3    = (const float*)d_in[6];
    const float* b3    = (const float*)d_in[7];
    float* out = (float*)d_out;

    unsigned short* H1  = (unsigned short*)d_ws;            // 100096*256 bf16
    unsigned short* W1i = H1 + (size_t)100096 * NFEAT;      // 65536 shorts
    unsigned short* W2i = W1i + 65536;                      // 65536 shorts

    prep<<<dim3(512), 256, 0, stream>>>(W1, W2, W1i, W2i, out);
    mlp1<<<dim3(NBLK), 1024, 0, stream>>>(A, W1i, b1, H1);
    mlp2<<<dim3(NBLK), 1024, 0, stream>>>(H1, W2i, b2, W3, b3, batch, out);
}